// Round 2
// baseline (275.854 us; speedup 1.0000x reference)
//
#include <hip/hip_runtime.h>
#include <hip/hip_cooperative_groups.h>

namespace cg = cooperative_groups;

#define NEG_SLOPE 0.2f
#define EPSV 1e-16f
#define NHEADS 8
#define NCH 16
#define BKT_SHIFT 8        // 256 nodes per bucket
#define BKT_NODES 256
#define CAP 8192           // per-bucket edge capacity (mean 4096, ~64 sigma slack)
#define BIN_EPB 4096       // edges per chunk in bin phase (16/thread)
#define MAX_BKT 512

struct BinSM  { int hist[MAX_BKT]; int gbase[MAX_BKT]; };                 // 4 KB
struct GathSM { unsigned int ed[CAP]; int cnt[BKT_NODES];
                int off[BKT_NODES]; int cur[BKT_NODES]; };                // 35 KB
union  SMU    { BinSM bin; GathSM g; };

// ---------------------------------------------------------------------------
// Fused cooperative kernel: P0 zero cursors | P1 bin | P2 sort+gather1+MLP |
// P3 gather2 straight out of the LDS-resident sorted lists.
// Grid == nbuckets (391): one block per bucket, all co-resident.
// Removes: setup kernel, sorted-src write-back (6.4MB W), binned re-read
// (6.4MB R), row meta (1.6MB), 3 kernel boundaries. h2 self value stays in
// a register across the grid sync.
// ---------------------------------------------------------------------------
__global__ __launch_bounds__(256) void gat_fused_kernel(
        int N, int E, const float* __restrict__ x, const int* __restrict__ ei,
        const float* __restrict__ W1, const float* __restrict__ as1,
        const float* __restrict__ ad1, const float* __restrict__ b1,
        const float* __restrict__ W2, const float* __restrict__ as2,
        const float* __restrict__ ad2, const float* __restrict__ b2,
        float* __restrict__ h2, int* __restrict__ bkt_cnt,
        unsigned int* __restrict__ binned, float* __restrict__ out) {
    cg::grid_group grid = cg::this_grid();
    __shared__ SMU sm;
    __shared__ float S1s[NHEADS], D1s[NHEADS], xloc[BKT_NODES];
    int b = blockIdx.x, t = threadIdx.x;
    int nbuckets = gridDim.x;

    // ---- P0: zero bucket cursors -----------------------------------------
    if (t == 0) bkt_cnt[b] = 0;
    grid.sync();

    // ---- P1: bin (one 4096-edge chunk per block, grid-stride for safety) --
    int nchunks = (E + BIN_EPB - 1) / BIN_EPB;
    for (int ch = b; ch < nchunks; ch += gridDim.x) {
        for (int i = t; i < nbuckets; i += 256) sm.bin.hist[i] = 0;
        __syncthreads();
        int base = ch * BIN_EPB;
        int lr[16];
#pragma unroll
        for (int k = 0; k < 4; ++k) {
            int idx = base + k * 1024 + t * 4;
            if (idx + 3 < E) {
                int4 d4 = *(const int4*)(ei + E + idx);
                lr[4*k+0] = atomicAdd(&sm.bin.hist[d4.x >> BKT_SHIFT], 1);
                lr[4*k+1] = atomicAdd(&sm.bin.hist[d4.y >> BKT_SHIFT], 1);
                lr[4*k+2] = atomicAdd(&sm.bin.hist[d4.z >> BKT_SHIFT], 1);
                lr[4*k+3] = atomicAdd(&sm.bin.hist[d4.w >> BKT_SHIFT], 1);
            } else {
                for (int u = 0; u < 4; ++u)
                    if (idx + u < E)
                        lr[4*k+u] = atomicAdd(&sm.bin.hist[ei[E + idx + u] >> BKT_SHIFT], 1);
            }
        }
        __syncthreads();
        for (int i = t; i < nbuckets; i += 256) {
            int c = sm.bin.hist[i];
            sm.bin.gbase[i] = c ? (i * CAP + atomicAdd(&bkt_cnt[i], c)) : 0;
        }
        __syncthreads();
#pragma unroll
        for (int k = 0; k < 4; ++k) {
            int idx = base + k * 1024 + t * 4;
            if (idx + 3 < E) {
                int4 s4 = *(const int4*)(ei + idx);
                int4 d4 = *(const int4*)(ei + E + idx);
                binned[sm.bin.gbase[d4.x >> BKT_SHIFT] + lr[4*k+0]] =
                    ((unsigned)s4.x << BKT_SHIFT) | (unsigned)(d4.x & (BKT_NODES-1));
                binned[sm.bin.gbase[d4.y >> BKT_SHIFT] + lr[4*k+1]] =
                    ((unsigned)s4.y << BKT_SHIFT) | (unsigned)(d4.y & (BKT_NODES-1));
                binned[sm.bin.gbase[d4.z >> BKT_SHIFT] + lr[4*k+2]] =
                    ((unsigned)s4.z << BKT_SHIFT) | (unsigned)(d4.z & (BKT_NODES-1));
                binned[sm.bin.gbase[d4.w >> BKT_SHIFT] + lr[4*k+3]] =
                    ((unsigned)s4.w << BKT_SHIFT) | (unsigned)(d4.w & (BKT_NODES-1));
            } else {
                for (int u = 0; u < 4; ++u)
                    if (idx + u < E) {
                        unsigned s = (unsigned)ei[idx + u];
                        int d = ei[E + idx + u];
                        binned[sm.bin.gbase[d >> BKT_SHIFT] + lr[4*k+u]] =
                            (s << BKT_SHIFT) | (unsigned)(d & (BKT_NODES-1));
                    }
            }
        }
        __syncthreads();
    }
    grid.sync();

    // ---- P2: per-bucket counting sort + layer-1 gather + fused MLP -------
    if (t < NHEADS) {
        float s = 0.f, d = 0.f;
        for (int c = 0; c < NCH; ++c) {
            float w = W1[t * NCH + c];
            s += w * as1[t * NCH + c];
            d += w * ad1[t * NCH + c];
        }
        S1s[t] = s; D1s[t] = d;
    }
    int node = (b << BKT_SHIFT) + t;
    xloc[t] = (node < N) ? x[node] : 0.f;
    sm.g.cnt[t] = 0;
    __syncthreads();
    int nE = bkt_cnt[b]; if (nE > CAP) nE = CAP;
    const unsigned int* bb = binned + (size_t)b * CAP;
    for (int j0 = 0; j0 < nE; j0 += 1024) {
        int idx = j0 + t * 4;
        if (idx + 3 < nE) {
            uint4 q = *(const uint4*)(bb + idx);
            atomicAdd(&sm.g.cnt[q.x & (BKT_NODES-1)], 1);
            atomicAdd(&sm.g.cnt[q.y & (BKT_NODES-1)], 1);
            atomicAdd(&sm.g.cnt[q.z & (BKT_NODES-1)], 1);
            atomicAdd(&sm.g.cnt[q.w & (BKT_NODES-1)], 1);
        } else {
            for (int u = 0; u < 4; ++u)
                if (idx + u < nE) atomicAdd(&sm.g.cnt[bb[idx + u] & (BKT_NODES-1)], 1);
        }
    }
    __syncthreads();
    int c = sm.g.cnt[t];
    sm.g.off[t] = c;
    __syncthreads();
    for (int o = 1; o < 256; o <<= 1) {
        int v = (t >= o) ? sm.g.off[t - o] : 0;
        __syncthreads();
        sm.g.off[t] += v;
        __syncthreads();
    }
    int o_excl = sm.g.off[t] - c;
    sm.g.off[t] = o_excl;
    sm.g.cur[t] = o_excl;
    __syncthreads();
    for (int j0 = 0; j0 < nE; j0 += 1024) {
        int idx = j0 + t * 4;
        if (idx + 3 < nE) {
            uint4 q = *(const uint4*)(bb + idx);
            sm.g.ed[atomicAdd(&sm.g.cur[q.x & (BKT_NODES-1)], 1)] = q.x >> BKT_SHIFT;
            sm.g.ed[atomicAdd(&sm.g.cur[q.y & (BKT_NODES-1)], 1)] = q.y >> BKT_SHIFT;
            sm.g.ed[atomicAdd(&sm.g.cur[q.z & (BKT_NODES-1)], 1)] = q.z >> BKT_SHIFT;
            sm.g.ed[atomicAdd(&sm.g.cur[q.w & (BKT_NODES-1)], 1)] = q.w >> BKT_SHIFT;
        } else {
            for (int u = 0; u < 4; ++u)
                if (idx + u < nE) {
                    unsigned v = bb[idx + u];
                    sm.g.ed[atomicAdd(&sm.g.cur[v & (BKT_NODES-1)], 1)] = v >> BKT_SHIFT;
                }
        }
    }
    __syncthreads();
    // per-node register gather, unroll-by-4
    float S1[NHEADS], A[NHEADS], den[NHEADS], num[NHEADS];
    float xn = xloc[t];
#pragma unroll
    for (int h = 0; h < NHEADS; ++h) {
        S1[h] = S1s[h];
        A[h] = xn * D1s[h];
        float e = xn * S1[h] + A[h];          // self-loop
        e = e > 0.f ? e : NEG_SLOPE * e;
        float ex = __expf(e);
        den[h] = ex + EPSV;
        num[h] = ex * xn;
    }
    int j = 0;
    for (; j + 4 <= c; j += 4) {
        unsigned e0 = sm.g.ed[o_excl + j + 0], e1 = sm.g.ed[o_excl + j + 1];
        unsigned e2 = sm.g.ed[o_excl + j + 2], e3 = sm.g.ed[o_excl + j + 3];
        float x0 = x[e0], x1 = x[e1], x2 = x[e2], x3 = x[e3];
#pragma unroll
        for (int h = 0; h < NHEADS; ++h) {
            float ea = x0 * S1[h] + A[h]; ea = ea > 0.f ? ea : NEG_SLOPE * ea;
            float eb = x1 * S1[h] + A[h]; eb = eb > 0.f ? eb : NEG_SLOPE * eb;
            float ec = x2 * S1[h] + A[h]; ec = ec > 0.f ? ec : NEG_SLOPE * ec;
            float ee = x3 * S1[h] + A[h]; ee = ee > 0.f ? ee : NEG_SLOPE * ee;
            float fa = __expf(ea), fb = __expf(eb), fc = __expf(ec), fd = __expf(ee);
            den[h] += (fa + fb) + (fc + fd);
            num[h] += (fa * x0 + fb * x1) + (fc * x2 + fd * x3);
        }
    }
    for (; j < c; ++j) {
        unsigned e0 = sm.g.ed[o_excl + j];
        float x0 = x[e0];
#pragma unroll
        for (int h = 0; h < NHEADS; ++h) {
            float ea = x0 * S1[h] + A[h];
            ea = ea > 0.f ? ea : NEG_SLOPE * ea;
            float fa = __expf(ea);
            den[h] += fa;
            num[h] += fa * x0;
        }
    }
    float acc = 0.f;
#pragma unroll
    for (int h = 0; h < NHEADS; ++h) {
        float z = num[h] / den[h];
#pragma unroll
        for (int cc = 0; cc < NCH; ++cc) {
            int k = h * NCH + cc;
            float vv = W1[k] * z + b1[k];
            vv = vv > 0.f ? vv : (__expf(vv) - 1.f);   // elu
            acc += vv * W2[k];
        }
    }
    if (node < N) h2[node] = acc;
    grid.sync();

    // ---- P3: layer-2 gather straight from the LDS-resident sorted lists --
    if (node < N) {
        float a_s = as2[0], a_d = ad2[0];
        float hn = acc;                       // own h2 value, kept in register
        float ad = hn * a_d;
        float e = hn * a_s + ad;              // self-loop
        e = e > 0.f ? e : NEG_SLOPE * e;
        float ex = __expf(e);
        float dn2 = ex + EPSV;
        float nm2 = ex * hn;
        int jj = 0;
        for (; jj + 4 <= c; jj += 4) {
            unsigned e0 = sm.g.ed[o_excl + jj + 0], e1 = sm.g.ed[o_excl + jj + 1];
            unsigned e2 = sm.g.ed[o_excl + jj + 2], e3 = sm.g.ed[o_excl + jj + 3];
            float h0 = h2[e0], h1 = h2[e1], h3 = h2[e2], h4 = h2[e3];
            float ea = h0 * a_s + ad; ea = ea > 0.f ? ea : NEG_SLOPE * ea;
            float eb = h1 * a_s + ad; eb = eb > 0.f ? eb : NEG_SLOPE * eb;
            float ec = h3 * a_s + ad; ec = ec > 0.f ? ec : NEG_SLOPE * ec;
            float ee = h4 * a_s + ad; ee = ee > 0.f ? ee : NEG_SLOPE * ee;
            float fa = __expf(ea), fb = __expf(eb), fc = __expf(ec), fd = __expf(ee);
            dn2 += (fa + fb) + (fc + fd);
            nm2 += (fa * h0 + fb * h1) + (fc * h3 + fd * h4);
        }
        for (; jj < c; ++jj) {
            unsigned e0 = sm.g.ed[o_excl + jj];
            float h0 = h2[e0];
            float ea = h0 * a_s + ad;
            ea = ea > 0.f ? ea : NEG_SLOPE * ea;
            float fa = __expf(ea);
            dn2 += fa;
            nm2 += fa * h0;
        }
        out[node] = nm2 / dn2 + b2[0];
    }
}

// ---------------------------------------------------------------------------
// Fallback path (round-0 proven kernels) if cooperative launch is rejected.
// ---------------------------------------------------------------------------
__global__ __launch_bounds__(512) void gat_setup_kernel(
        const float* __restrict__ W1, const float* __restrict__ as1,
        const float* __restrict__ ad1, float* __restrict__ S1,
        float* __restrict__ D1, int* __restrict__ bkt_cnt, int nbuckets) {
    int t = threadIdx.x;
    for (int i = t; i < nbuckets; i += 512) bkt_cnt[i] = 0;
    if (t < NHEADS) {
        float s = 0.f, d = 0.f;
        for (int c = 0; c < NCH; ++c) {
            float w = W1[t * NCH + c];
            s += w * as1[t * NCH + c];
            d += w * ad1[t * NCH + c];
        }
        S1[t] = s;
        D1[t] = d;
    }
}

__global__ __launch_bounds__(256) void gat_bin_kernel(
        const int* __restrict__ ei, int E, int nbuckets,
        int* __restrict__ bkt_cnt, unsigned int* __restrict__ binned) {
    __shared__ int hist[MAX_BKT];
    __shared__ int gbase[MAX_BKT];
    int t = threadIdx.x;
    for (int i = t; i < nbuckets; i += 256) hist[i] = 0;
    __syncthreads();
    int base = blockIdx.x * BIN_EPB;
    int lr[16];
#pragma unroll
    for (int k = 0; k < 4; ++k) {
        int idx = base + k * 1024 + t * 4;
        if (idx + 3 < E) {
            int4 d4 = *(const int4*)(ei + E + idx);
            lr[4*k+0] = atomicAdd(&hist[d4.x >> BKT_SHIFT], 1);
            lr[4*k+1] = atomicAdd(&hist[d4.y >> BKT_SHIFT], 1);
            lr[4*k+2] = atomicAdd(&hist[d4.z >> BKT_SHIFT], 1);
            lr[4*k+3] = atomicAdd(&hist[d4.w >> BKT_SHIFT], 1);
        } else {
            for (int u = 0; u < 4; ++u)
                if (idx + u < E)
                    lr[4*k+u] = atomicAdd(&hist[ei[E + idx + u] >> BKT_SHIFT], 1);
        }
    }
    __syncthreads();
    for (int i = t; i < nbuckets; i += 256) {
        int c = hist[i];
        gbase[i] = c ? (i * CAP + atomicAdd(&bkt_cnt[i], c)) : 0;
    }
    __syncthreads();
#pragma unroll
    for (int k = 0; k < 4; ++k) {
        int idx = base + k * 1024 + t * 4;
        if (idx + 3 < E) {
            int4 s4 = *(const int4*)(ei + idx);
            int4 d4 = *(const int4*)(ei + E + idx);
            binned[gbase[d4.x >> BKT_SHIFT] + lr[4*k+0]] =
                ((unsigned)s4.x << BKT_SHIFT) | (unsigned)(d4.x & (BKT_NODES-1));
            binned[gbase[d4.y >> BKT_SHIFT] + lr[4*k+1]] =
                ((unsigned)s4.y << BKT_SHIFT) | (unsigned)(d4.y & (BKT_NODES-1));
            binned[gbase[d4.z >> BKT_SHIFT] + lr[4*k+2]] =
                ((unsigned)s4.z << BKT_SHIFT) | (unsigned)(d4.z & (BKT_NODES-1));
            binned[gbase[d4.w >> BKT_SHIFT] + lr[4*k+3]] =
                ((unsigned)s4.w << BKT_SHIFT) | (unsigned)(d4.w & (BKT_NODES-1));
        } else {
            for (int u = 0; u < 4; ++u)
                if (idx + u < E) {
                    unsigned s = (unsigned)ei[idx + u];
                    int d = ei[E + idx + u];
                    binned[gbase[d >> BKT_SHIFT] + lr[4*k+u]] =
                        (s << BKT_SHIFT) | (unsigned)(d & (BKT_NODES-1));
                }
        }
    }
}

__global__ __launch_bounds__(256) void gat_gather1_kernel(
        int N, const float* __restrict__ x,
        unsigned int* __restrict__ binned, const int* __restrict__ bkt_cnt,
        const float* __restrict__ S1g, const float* __restrict__ D1g,
        const float* __restrict__ W1, const float* __restrict__ b1,
        const float* __restrict__ W2, float* __restrict__ h2out,
        int* __restrict__ row_start, int* __restrict__ row_deg) {
    __shared__ unsigned int ed[CAP];
    __shared__ int cnt[BKT_NODES];
    __shared__ int off[BKT_NODES];
    __shared__ int cur[BKT_NODES];
    __shared__ float xloc[BKT_NODES];
    int b = blockIdx.x, t = threadIdx.x;
    int node = (b << BKT_SHIFT) + t;
    xloc[t] = (node < N) ? x[node] : 0.f;
    cnt[t] = 0;
    __syncthreads();
    int nE = bkt_cnt[b]; if (nE > CAP) nE = CAP;
    const unsigned int* bb = binned + (size_t)b * CAP;
    for (int j0 = 0; j0 < nE; j0 += 1024) {
        int idx = j0 + t * 4;
        if (idx + 3 < nE) {
            uint4 q = *(const uint4*)(bb + idx);
            atomicAdd(&cnt[q.x & (BKT_NODES-1)], 1);
            atomicAdd(&cnt[q.y & (BKT_NODES-1)], 1);
            atomicAdd(&cnt[q.z & (BKT_NODES-1)], 1);
            atomicAdd(&cnt[q.w & (BKT_NODES-1)], 1);
        } else {
            for (int u = 0; u < 4; ++u)
                if (idx + u < nE) atomicAdd(&cnt[bb[idx + u] & (BKT_NODES-1)], 1);
        }
    }
    __syncthreads();
    int c = cnt[t];
    off[t] = c;
    __syncthreads();
    for (int o = 1; o < 256; o <<= 1) {
        int v = (t >= o) ? off[t - o] : 0;
        __syncthreads();
        off[t] += v;
        __syncthreads();
    }
    int o_excl = off[t] - c;
    off[t] = o_excl;
    cur[t] = o_excl;
    __syncthreads();
    for (int j0 = 0; j0 < nE; j0 += 1024) {
        int idx = j0 + t * 4;
        if (idx + 3 < nE) {
            uint4 q = *(const uint4*)(bb + idx);
            ed[atomicAdd(&cur[q.x & (BKT_NODES-1)], 1)] = q.x >> BKT_SHIFT;
            ed[atomicAdd(&cur[q.y & (BKT_NODES-1)], 1)] = q.y >> BKT_SHIFT;
            ed[atomicAdd(&cur[q.z & (BKT_NODES-1)], 1)] = q.z >> BKT_SHIFT;
            ed[atomicAdd(&cur[q.w & (BKT_NODES-1)], 1)] = q.w >> BKT_SHIFT;
        } else {
            for (int u = 0; u < 4; ++u)
                if (idx + u < nE) {
                    unsigned v = bb[idx + u];
                    ed[atomicAdd(&cur[v & (BKT_NODES-1)], 1)] = v >> BKT_SHIFT;
                }
        }
    }
    __syncthreads();
    for (int j0 = 0; j0 < nE; j0 += 1024) {
        int idx = j0 + t * 4;
        if (idx + 3 < nE) {
            *(uint4*)(binned + (size_t)b * CAP + idx) = *(const uint4*)(ed + idx);
        } else {
            for (int u = 0; u < 4; ++u)
                if (idx + u < nE) binned[(size_t)b * CAP + idx + u] = ed[idx + u];
        }
    }
    if (node < N) {
        row_start[node] = b * CAP + o_excl;
        row_deg[node] = c;
    }
    float S1[NHEADS], A[NHEADS], den[NHEADS], num[NHEADS];
    float xn = xloc[t];
#pragma unroll
    for (int h = 0; h < NHEADS; ++h) {
        S1[h] = S1g[h];
        A[h] = xn * D1g[h];
        float e = xn * S1[h] + A[h];
        e = e > 0.f ? e : NEG_SLOPE * e;
        float ex = __expf(e);
        den[h] = ex + EPSV;
        num[h] = ex * xn;
    }
    int j = 0;
    for (; j + 4 <= c; j += 4) {
        unsigned e0 = ed[o_excl + j + 0], e1 = ed[o_excl + j + 1];
        unsigned e2 = ed[o_excl + j + 2], e3 = ed[o_excl + j + 3];
        float x0 = x[e0], x1 = x[e1], x2 = x[e2], x3 = x[e3];
#pragma unroll
        for (int h = 0; h < NHEADS; ++h) {
            float ea = x0 * S1[h] + A[h]; ea = ea > 0.f ? ea : NEG_SLOPE * ea;
            float eb = x1 * S1[h] + A[h]; eb = eb > 0.f ? eb : NEG_SLOPE * eb;
            float ec = x2 * S1[h] + A[h]; ec = ec > 0.f ? ec : NEG_SLOPE * ec;
            float ee = x3 * S1[h] + A[h]; ee = ee > 0.f ? ee : NEG_SLOPE * ee;
            float fa = __expf(ea), fb = __expf(eb), fc = __expf(ec), fd = __expf(ee);
            den[h] += (fa + fb) + (fc + fd);
            num[h] += (fa * x0 + fb * x1) + (fc * x2 + fd * x3);
        }
    }
    for (; j < c; ++j) {
        unsigned e0 = ed[o_excl + j];
        float x0 = x[e0];
#pragma unroll
        for (int h = 0; h < NHEADS; ++h) {
            float ea = x0 * S1[h] + A[h];
            ea = ea > 0.f ? ea : NEG_SLOPE * ea;
            float fa = __expf(ea);
            den[h] += fa;
            num[h] += fa * x0;
        }
    }
    if (node >= N) return;
    float acc = 0.f;
#pragma unroll
    for (int h = 0; h < NHEADS; ++h) {
        float z = num[h] / den[h];
#pragma unroll
        for (int cc = 0; cc < NCH; ++cc) {
            int k = h * NCH + cc;
            float vv = W1[k] * z + b1[k];
            vv = vv > 0.f ? vv : (__expf(vv) - 1.f);
            acc += vv * W2[k];
        }
    }
    h2out[node] = acc;
}

__global__ __launch_bounds__(256) void gat_gather2_kernel(
        int N, const float* __restrict__ h2,
        const unsigned int* __restrict__ binned,
        const int* __restrict__ row_start, const int* __restrict__ row_deg,
        const float* __restrict__ as2p, const float* __restrict__ ad2p,
        const float* __restrict__ b2, float* __restrict__ out) {
    int n = blockIdx.x * blockDim.x + threadIdx.x;
    if (n >= N) return;
    float a_s = as2p[0], a_d = ad2p[0];
    float hn = h2[n];
    float ad = hn * a_d;
    float e = hn * a_s + ad;
    e = e > 0.f ? e : NEG_SLOPE * e;
    float ex = __expf(e);
    float den = ex + EPSV;
    float num = ex * hn;
    int st = row_start[n], dg = row_deg[n];
    int j = 0;
    for (; j + 4 <= dg; j += 4) {
        unsigned e0 = binned[st + j + 0], e1 = binned[st + j + 1];
        unsigned e2 = binned[st + j + 2], e3 = binned[st + j + 3];
        float h0 = h2[e0], h1 = h2[e1], h3 = h2[e2], h4 = h2[e3];
        float ea = h0 * a_s + ad; ea = ea > 0.f ? ea : NEG_SLOPE * ea;
        float eb = h1 * a_s + ad; eb = eb > 0.f ? eb : NEG_SLOPE * eb;
        float ec = h3 * a_s + ad; ec = ec > 0.f ? ec : NEG_SLOPE * ec;
        float ee = h4 * a_s + ad; ee = ee > 0.f ? ee : NEG_SLOPE * ee;
        float fa = __expf(ea), fb = __expf(eb), fc = __expf(ec), fd = __expf(ee);
        den += (fa + fb) + (fc + fd);
        num += (fa * h0 + fb * h1) + (fc * h3 + fd * h4);
    }
    for (; j < dg; ++j) {
        unsigned e0 = binned[st + j];
        float h0 = h2[e0];
        float ea = h0 * a_s + ad;
        ea = ea > 0.f ? ea : NEG_SLOPE * ea;
        float fa = __expf(ea);
        den += fa;
        num += fa * h0;
    }
    out[n] = num / den + b2[0];
}

extern "C" void kernel_launch(void* const* d_in, const int* in_sizes, int n_in,
                              void* d_out, int out_size, void* d_ws, size_t ws_size,
                              hipStream_t stream) {
    const float* x   = (const float*)d_in[0];
    const int*   ei  = (const int*)d_in[1];
    const float* W1  = (const float*)d_in[2];
    const float* as1 = (const float*)d_in[3];
    const float* ad1 = (const float*)d_in[4];
    const float* b1  = (const float*)d_in[5];
    const float* W2  = (const float*)d_in[6];
    const float* as2 = (const float*)d_in[7];
    const float* ad2 = (const float*)d_in[8];
    const float* b2  = (const float*)d_in[9];
    float* out = (float*)d_out;

    int N = in_sizes[0];       // 100000
    int E = in_sizes[1] / 2;   // 1600000

    int nbuckets = (N + BKT_NODES - 1) >> BKT_SHIFT;   // 391

    // Workspace: S1[8]f | D1[8]f | h2[N]f | row_start[N]i | row_deg[N]i |
    // bkt_cnt[nbuckets]i | binned[nbuckets*CAP]u
    float* S1        = (float*)d_ws;
    float* D1        = S1 + 8;
    float* h2        = D1 + 8;
    int*   row_start = (int*)(h2 + N);
    int*   row_deg   = row_start + N;
    int*   bkt_cnt   = row_deg + N;
    unsigned int* binned = (unsigned int*)(bkt_cnt + nbuckets);

    // Fused cooperative path: grid == nbuckets (391), all blocks co-resident
    // (37 KB LDS -> >=2 blocks/CU; need 1.53).
    void* args[] = { (void*)&N, (void*)&E, (void*)&x, (void*)&ei,
                     (void*)&W1, (void*)&as1, (void*)&ad1, (void*)&b1,
                     (void*)&W2, (void*)&as2, (void*)&ad2, (void*)&b2,
                     (void*)&h2, (void*)&bkt_cnt, (void*)&binned, (void*)&out };
    hipError_t err = hipLaunchCooperativeKernel(
        gat_fused_kernel, dim3(nbuckets), dim3(256), args, 0u, stream);
    if (err == hipSuccess) return;

    // Fallback: proven 4-kernel path (round-0 structure).
    int nbin = (E + BIN_EPB - 1) / BIN_EPB;
    int nb   = (N + 255) / 256;
    gat_setup_kernel<<<1, 512, 0, stream>>>(W1, as1, ad1, S1, D1,
                                            bkt_cnt, nbuckets);
    gat_bin_kernel<<<nbin, 256, 0, stream>>>(ei, E, nbuckets, bkt_cnt, binned);
    gat_gather1_kernel<<<nbuckets, 256, 0, stream>>>(N, x, binned, bkt_cnt,
                                                     S1, D1, W1, b1, W2, h2,
                                                     row_start, row_deg);
    gat_gather2_kernel<<<nb, 256, 0, stream>>>(N, h2, binned, row_start, row_deg,
                                               as2, ad2, b2, out);
}